// Round 1
// 365.275 us; speedup vs baseline: 1.0946x; 1.0946x over previous
//
#include <hip/hip_runtime.h>
#include <math.h>

#define EPS 1e-5f

typedef short short8 __attribute__((ext_vector_type(8)));
typedef __bf16 bf16x8 __attribute__((ext_vector_type(8)));
typedef float f32x4  __attribute__((ext_vector_type(4)));

__device__ __forceinline__ float lrelu(float x){ return x >= 0.f ? x : 0.2f*x; }

// round-to-nearest-even f32 -> bf16 bits
__device__ __forceinline__ short f2bf_s(float x){
    unsigned u = __float_as_uint(x);
    unsigned r = (u + 0x7FFFu + ((u >> 16) & 1u)) >> 16;
    return (short)r;
}
__device__ __forceinline__ float bfs2f(short h){
    return __uint_as_float(((unsigned)(unsigned short)h) << 16);
}

__device__ __forceinline__ f32x4 mfma16(bf16x8 a, bf16x8 b, f32x4 c){
    return __builtin_amdgcn_mfma_f32_16x16x32_bf16(a, b, c, 0, 0, 0);
}

// -----------------------------------------------------------------------------
// Feature path phase A: conv1x1 (256->64) + bias, both sides (fa,fb) in one
// launch, LDS-tiled, coalesced. Per-(side,n,co) sum/sumsq via wave-shuffle
// reduce + atomics. Y layout: [side][n][p][co].
// grid = 256 = side(2) x n(2) x pchunk(64 of 64 p); block 256 = 64 p x 4 cog.
__global__ __launch_bounds__(256,2) void feat_conv(
    const float* __restrict__ fa_raw, const float* __restrict__ fb_raw,
    const float* __restrict__ Wa, const float* __restrict__ Wb,
    const float* __restrict__ ba, const float* __restrict__ bb,
    float* __restrict__ Y, float* __restrict__ FSUM)   // FSUM[4*64][2]
{
    __shared__ float wS[256*65];   // W transposed [ci][co], pad 65
    __shared__ float xS[16*64];    // x tile [ci_l][p]

    int blk = blockIdx.x;
    int pch = blk & 63, n = (blk>>6)&1, side = blk>>7;
    int p0 = pch*64;
    const float* x    = (side ? fb_raw : fa_raw) + (size_t)n*256*4096 + p0;
    const float* W    = side ? Wb : Wa;
    const float* bias = side ? bb : ba;
    int tid = threadIdx.x;

    #pragma unroll
    for (int it=0; it<64; it++){
        int idx = it*256 + tid;
        int co = idx >> 8, ci = idx & 255;
        wS[ci*65 + co] = W[idx];
    }

    int pl = tid & 63, cog = tid >> 6;
    float acc[16];
    #pragma unroll
    for (int j=0;j<16;j++) acc[j] = 0.f;

    for (int cb=0; cb<16; cb++){
        __syncthreads();
        #pragma unroll
        for (int it=0; it<4; it++){
            int idx = it*256 + tid;
            int cl = idx >> 6, pp = idx & 63;
            xS[idx] = x[(size_t)(cb*16+cl)*4096 + pp];
        }
        __syncthreads();
        #pragma unroll
        for (int cl=0; cl<16; cl++){
            float xr = xS[cl*64 + pl];
            const float* wr = &wS[(cb*16+cl)*65 + cog*16];
            #pragma unroll
            for (int j=0;j<16;j++) acc[j] = fmaf(xr, wr[j], acc[j]);
        }
    }

    int pair = side*2 + n;
    #pragma unroll
    for (int j=0;j<16;j++){
        acc[j] += bias[cog*16+j];
        float v = acc[j], v2 = v*v;
        #pragma unroll
        for (int off=1; off<64; off<<=1){
            v  += __shfl_xor(v,  off);
            v2 += __shfl_xor(v2, off);
        }
        if (pl == 0){
            atomicAdd(&FSUM[(pair*64 + cog*16 + j)*2],   v);
            atomicAdd(&FSUM[(pair*64 + cog*16 + j)*2+1], v2);
        }
    }

    float* yr = Y + ((size_t)pair*4096 + p0 + pl)*64 + cog*16;
    #pragma unroll
    for (int j4=0;j4<4;j4++)
        *(float4*)(yr + j4*4) = make_float4(acc[j4*4],acc[j4*4+1],acc[j4*4+2],acc[j4*4+3]);
}

// Phase C: y = lrelu((y-m)*rstd) in place + per-channel sums for re-centering.
// Stats computed inline from FSUM (fstats kernel fused away).
// grid = 256 blocks x 64 rows each (16384 rows total).
__global__ __launch_bounds__(256) void feat_apply(
    float* __restrict__ Y, const float* __restrict__ FSUM, float* __restrict__ M2SUM)
{
    __shared__ float red[256];
    int tid = threadIdx.x;
    size_t base = (size_t)blockIdx.x*4096;
    int pair = (int)(base >> 18);          // 4096*64 elems per pair-plane
    int co = tid & 63;
    int ch = pair*64 + co;
    float m   = FSUM[ch*2]   * (1.f/4096.f);
    float var = FSUM[ch*2+1] * (1.f/4096.f) - m*m;
    float inv = rsqrtf(var + EPS);
    float asum = 0.f;
    #pragma unroll
    for (int it=0; it<16; it++){
        size_t idx = base + it*256 + tid;
        float y2 = lrelu((Y[idx]-m)*inv);
        Y[idx] = y2;
        asum += y2;
    }
    red[tid] = asum; __syncthreads();
    if (tid < 64)
        atomicAdd(&M2SUM[pair*64 + tid], red[tid]+red[tid+64]+red[tid+128]+red[tid+192]);
}

// Phase E: per-position: subtract spatial mean, L2-normalize over channels,
// then pack directly into PK in the corr-LDS fragment layout (bf16 hi|lo).
// PK per (pair,qb) block: 16384 shorts = hi[1024*8] | lo[1024*8],
// chunk idx = g*128 + c*16 + r16  (row rr = g*16+r16, cols c*8..c*8+7).
// one thread per (side,n,p) row; 16384 threads.
__global__ void feat_finish(const float* __restrict__ Y, const float* __restrict__ M2SUM,
                            short* __restrict__ PK)
{
    int r = blockIdx.x*256 + threadIdx.x;
    int pair = r >> 12;
    int p = r & 4095;
    const float4* m4 = (const float4*)(M2SUM + pair*64);
    const float4* r4 = (const float4*)(Y + (size_t)r*64);
    float s = 0.f;
    float4 v[16];
    #pragma unroll
    for (int i=0;i<16;i++){
        float4 t = r4[i], mm = m4[i];
        t.x -= mm.x*(1.f/4096.f); t.y -= mm.y*(1.f/4096.f);
        t.z -= mm.z*(1.f/4096.f); t.w -= mm.w*(1.f/4096.f);
        v[i] = t;
        s += t.x*t.x + t.y*t.y + t.z*t.z + t.w*t.w;
    }
    float inv = 1.f/(sqrtf(s)+EPS);
    #pragma unroll
    for (int i=0;i<16;i++){ v[i].x*=inv; v[i].y*=inv; v[i].z*=inv; v[i].w*=inv; }

    int qb = p >> 7, rr = p & 127, g = rr >> 4, rl = rr & 15;
    short* blk = PK + (((size_t)pair*32 + qb) << 14);   // *16384 shorts
    #pragma unroll
    for (int c=0;c<8;c++){
        float x[8] = {v[2*c].x, v[2*c].y, v[2*c].z, v[2*c].w,
                      v[2*c+1].x, v[2*c+1].y, v[2*c+1].z, v[2*c+1].w};
        short8 h, l;
        #pragma unroll
        for (int j=0;j<8;j++){
            short hh = f2bf_s(x[j]);
            h[j] = hh;
            l[j] = f2bf_s(x[j] - bfs2f(hh));
        }
        int idx = g*128 + c*16 + rl;
        *(short8*)(blk + idx*8)        = h;
        *(short8*)(blk + 8192 + idx*8) = l;
    }
}

// -----------------------------------------------------------------------------
// generic 3x3 conv, Cin=Cout=3 (fc path, reflect pad, stride 2)
template<int STRIDE, bool REFLECT>
__global__ void conv3_kernel(const float* __restrict__ in_, int H, int Wd,
                             const float* __restrict__ wgt,
                             const float* __restrict__ bias,
                             float* __restrict__ out, float* __restrict__ sums)
{
    int oH = (H-1)/STRIDE + 1, oW = (Wd-1)/STRIDE + 1;
    int tid = threadIdx.x;
    size_t idx = (size_t)blockIdx.x*256 + tid;
    int ow = (int)(idx % oW); size_t t = idx / oW;
    int oh = (int)(t % oH); t /= oH;
    int co = (int)(t % 3); int n = (int)(t/3);
    float w[27];
    #pragma unroll
    for (int i=0;i<27;i++) w[i] = wgt[co*27 + i];
    float acc = bias[co];
    #pragma unroll
    for (int ci=0;ci<3;ci++){
        size_t base = ((size_t)(n*3+ci))*H*Wd;
        #pragma unroll
        for (int kh=0;kh<3;kh++){
            int ih = oh*STRIDE + kh - 1;
            if (REFLECT) ih = ih<0 ? -ih : (ih>=H ? 2*H-2-ih : ih);
            #pragma unroll
            for (int kw=0;kw<3;kw++){
                int iw = ow*STRIDE + kw - 1;
                if (REFLECT) iw = iw<0 ? -iw : (iw>=Wd ? 2*Wd-2-iw : iw);
                bool ok = REFLECT || (ih>=0 && ih<H && iw>=0 && iw<Wd);
                if (ok) acc += w[(ci*3+kh)*3+kw] * in_[base + (size_t)ih*Wd + iw];
            }
        }
    }
    out[idx] = acc;
    __shared__ float red[256];
    red[tid] = acc; __syncthreads();
    for (int o=128;o>0;o>>=1){ if(tid<o) red[tid]+=red[tid+o]; __syncthreads(); }
    float blockSum = red[0]; __syncthreads();
    red[tid] = acc*acc; __syncthreads();
    for (int o=128;o>0;o>>=1){ if(tid<o) red[tid]+=red[tid+o]; __syncthreads(); }
    if (tid==0){
        int pair = n*3+co;
        atomicAdd(&sums[pair*2],   blockSum);
        atomicAdd(&sums[pair*2+1], red[0]);
    }
}

// fused bilinear-up2x (align_corners) + zero-pad 3x3 conv, Cin=Cout=3.
// input planes H x H; output (2H)x(2H). Identical fp32 math to the old
// up2x_kernel -> conv3_kernel<1,false> pipeline.
template<int H>
__global__ __launch_bounds__(256) void upconv3_kernel(
    const float* __restrict__ in_, const float* __restrict__ wgt,
    const float* __restrict__ bias, float* __restrict__ out,
    float* __restrict__ sums)
{
    const int oH = 2*H;
    int tid = threadIdx.x;
    size_t idx = (size_t)blockIdx.x*256 + tid;
    int ow = (int)(idx % oH); size_t t = idx / oH;
    int oh = (int)(t % oH); t /= oH;
    int co = (int)(t % 3); int n = (int)(t/3);

    float w[27];
    #pragma unroll
    for (int i=0;i<27;i++) w[i] = wgt[co*27 + i];

    int i0[3], i1[3], j0[3], j1[3];
    float fh[3], fw[3];
    bool vh[3], vw[3];
    #pragma unroll
    for (int k=0;k<3;k++){
        int ih = oh + k - 1;
        vh[k] = (ih>=0 && ih<oH);
        int ihc = vh[k] ? ih : 0;
        float ph = (float)ihc * (float)(H-1) / (float)(oH-1);
        i0[k] = (int)ph; i1[k] = min(i0[k]+1, H-1); fh[k] = ph - (float)i0[k];
        int iw = ow + k - 1;
        vw[k] = (iw>=0 && iw<oH);
        int iwc = vw[k] ? iw : 0;
        float pw = (float)iwc * (float)(H-1) / (float)(oH-1);
        j0[k] = (int)pw; j1[k] = min(j0[k]+1, H-1); fw[k] = pw - (float)j0[k];
    }

    float acc = bias[co];
    #pragma unroll
    for (int ci=0;ci<3;ci++){
        const float* p = in_ + ((size_t)(n*3+ci))*H*H;
        #pragma unroll
        for (int kh=0;kh<3;kh++){
            if (!vh[kh]) continue;
            const float* r0 = p + (size_t)i0[kh]*H;
            const float* r1 = p + (size_t)i1[kh]*H;
            #pragma unroll
            for (int kw=0;kw<3;kw++){
                if (!vw[kw]) continue;
                float v00=r0[j0[kw]], v01=r0[j1[kw]];
                float v10=r1[j0[kw]], v11=r1[j1[kw]];
                float v0 = v00 + (v01-v00)*fw[kw];
                float v1 = v10 + (v11-v10)*fw[kw];
                float u  = v0 + (v1-v0)*fh[kh];
                acc += w[(ci*3+kh)*3+kw] * u;
            }
        }
    }
    out[idx] = acc;
    __shared__ float red[256];
    red[tid] = acc; __syncthreads();
    for (int o=128;o>0;o>>=1){ if(tid<o) red[tid]+=red[tid+o]; __syncthreads(); }
    float blockSum = red[0]; __syncthreads();
    red[tid] = acc*acc; __syncthreads();
    for (int o=128;o>0;o>>=1){ if(tid<o) red[tid]+=red[tid+o]; __syncthreads(); }
    if (tid==0){
        int pair = n*3+co;
        atomicAdd(&sums[pair*2],   blockSum);
        atomicAdd(&sums[pair*2+1], red[0]);
    }
}

// instance-norm apply with inline stats (instats kernel fused away)
__global__ void inapply_kernel(const float* __restrict__ in, const float* __restrict__ sums,
                               int planeSize, float cntInv, float* __restrict__ out)
{
    size_t idx = (size_t)blockIdx.x*256 + threadIdx.x;
    int pair = (int)(idx / planeSize);
    float m = sums[pair*2]*cntInv;
    float v = sums[pair*2+1]*cntInv - m*m;
    float inv = rsqrtf(v + EPS);
    out[idx] = lrelu((in[idx]-m)*inv);
}

// -----------------------------------------------------------------------------
// MFMA correlation, 3-term bf16 split, two-pass recompute.
// Staging is now a straight short8 copy from pre-packed PK (no convert ALU).
template<int PASS>
__global__ __launch_bounds__(256,2) void corr_mfma(
    const short* __restrict__ PK,
    float* __restrict__ corr, float* __restrict__ SSUM,
    const float* __restrict__ fc, float* __restrict__ WARP)
{
    __shared__ short lds[32768];   // 64KB: fb_hi|fb_lo|fa_hi|fa_lo, 8192 each

    int blk = blockIdx.x;
    int qb = blk & 31, pb = (blk >> 5) & 31, n = blk >> 10;
    int tid = threadIdx.x;

    // fb = side 1 -> pair 2+n ; fa = side 0 -> pair n
    const short* pkB = PK + (((size_t)(2+n)*32 + pb) << 14);
    const short* pkA = PK + (((size_t)( n )*32 + qb) << 14);
    #pragma unroll
    for (int it=0; it<16; it++){
        int cid = it*256 + tid;      // 0..4095 short8 chunks
        int side = cid >> 11;        // 0 = fb -> lds[0..16384), 1 = fa -> +16384
        int off  = (cid & 2047)*8;
        short8 vv = *(const short8*)((side ? pkA : pkB) + off);
        *(short8*)(lds + side*16384 + off) = vv;
    }
    __syncthreads();

    int wave = tid >> 6, lane = tid & 63;
    int wp = wave >> 1, wq = wave & 1;
    int quad = lane >> 4, l16 = lane & 15;

    f32x4 acc[4][4];
    #pragma unroll
    for (int pt=0;pt<4;pt++)
        #pragma unroll
        for (int qt=0;qt<4;qt++)
            acc[pt][qt] = (f32x4){0.f,0.f,0.f,0.f};

    #pragma unroll
    for (int kc=0;kc<2;kc++){
        int cc = kc*4 + quad;
        bf16x8 Ah[4], Al[4], Bh[4], Bl[4];
        #pragma unroll
        for (int t4=0;t4<4;t4++){
            int offA = (((wp*4+t4)*8 + cc)*16 + l16)*8;
            Ah[t4] = (bf16x8)(*(const short8*)(lds + offA));
            Al[t4] = (bf16x8)(*(const short8*)(lds + 8192 + offA));
            int offB = 16384 + (((wq*4+t4)*8 + cc)*16 + l16)*8;
            Bh[t4] = (bf16x8)(*(const short8*)(lds + offB));
            Bl[t4] = (bf16x8)(*(const short8*)(lds + 8192 + offB));
        }
        #pragma unroll
        for (int pt=0;pt<4;pt++)
            #pragma unroll
            for (int qt=0;qt<4;qt++){
                acc[pt][qt] = mfma16(Ah[pt], Bh[qt], acc[pt][qt]);
                acc[pt][qt] = mfma16(Ah[pt], Bl[qt], acc[pt][qt]);
                acc[pt][qt] = mfma16(Al[pt], Bh[qt], acc[pt][qt]);
            }
    }

    if (PASS == 0){
        float colsum[4] = {0.f,0.f,0.f,0.f};
        #pragma unroll
        for (int pt=0;pt<4;pt++)
            #pragma unroll
            for (int qt=0;qt<4;qt++)
                #pragma unroll
                for (int i=0;i<4;i++)
                    colsum[qt] += __expf(fmaf(acc[pt][qt][i], 100.f, -64.f));
        #pragma unroll
        for (int qt=0;qt<4;qt++){
            float v = colsum[qt];
            v += __shfl_xor(v, 16);
            v += __shfl_xor(v, 32);
            if (lane < 16)
                atomicAdd(&SSUM[n*4096 + qb*128 + wq*64 + qt*16 + lane], v);
        }
    } else {
        float inv4[4];
        int qoff = n*4096 + qb*128 + wq*64 + l16;
        #pragma unroll
        for (int qt=0;qt<4;qt++) inv4[qt] = 1.f / SSUM[qoff + qt*16];
        float wa0[4]={0,0,0,0}, wa1[4]={0,0,0,0}, wa2[4]={0,0,0,0};
        const float* fcb = fc + (size_t)n*12288;
        float* corrN = corr + (size_t)n*4096*4096;
        #pragma unroll
        for (int pt=0;pt<4;pt++){
            #pragma unroll
            for (int i=0;i<4;i++){
                int p = pb*128 + wp*64 + pt*16 + quad*4 + i;
                float f0 = fcb[p], f1 = fcb[4096+p], f2 = fcb[8192+p];
                float* rowp = corrN + (size_t)p*4096 + qb*128 + wq*64 + l16;
                #pragma unroll
                for (int qt=0;qt<4;qt++){
                    float u = __expf(fmaf(acc[pt][qt][i], 100.f, -64.f)) * inv4[qt];
                    __builtin_nontemporal_store(u, &rowp[qt*16]);
                    wa0[qt] += f0*u; wa1[qt] += f1*u; wa2[qt] += f2*u;
                }
            }
        }
        #pragma unroll
        for (int qt=0;qt<4;qt++){
            float v0 = wa0[qt], v1 = wa1[qt], v2 = wa2[qt];
            v0 += __shfl_xor(v0,16); v0 += __shfl_xor(v0,32);
            v1 += __shfl_xor(v1,16); v1 += __shfl_xor(v1,32);
            v2 += __shfl_xor(v2,16); v2 += __shfl_xor(v2,32);
            if (lane < 16){
                int q = qb*128 + wq*64 + qt*16 + lane;
                atomicAdd(&WARP[(size_t)n*12288 +        q], v0);
                atomicAdd(&WARP[(size_t)n*12288 + 4096 + q], v1);
                atomicAdd(&WARP[(size_t)n*12288 + 8192 + q], v2);
            }
        }
    }
}

// -----------------------------------------------------------------------------
extern "C" void kernel_launch(void* const* d_in, const int* in_sizes, int n_in,
                              void* d_out, int out_size, void* d_ws, size_t ws_size,
                              hipStream_t stream)
{
    const float* fa_raw = (const float*)d_in[0];
    const float* fb_raw = (const float*)d_in[1];
    const float* fc_raw = (const float*)d_in[2];
    const float* Wa  = (const float*)d_in[3];
    const float* ba  = (const float*)d_in[4];
    const float* Wb  = (const float*)d_in[5];
    const float* bb  = (const float*)d_in[6];
    const float* Wc1 = (const float*)d_in[7];
    const float* bc1 = (const float*)d_in[8];
    const float* Wc2 = (const float*)d_in[9];
    const float* bc2 = (const float*)d_in[10];
    const float* Wu1 = (const float*)d_in[11];
    const float* bu1 = (const float*)d_in[12];
    const float* Wu2 = (const float*)d_in[13];
    const float* bu2 = (const float*)d_in[14];

    float* ws    = (float*)d_ws;
    float* FEAT  = ws;                  // 1048576 = [side][n][4096][64]
    float* CONV1 = FEAT  + 1048576;     // 98304
    float* FC64  = CONV1 + 98304;       // 24576
    float* CONV2 = FC64  + 24576;       // 98304
    float* CONV3 = CONV2 + 98304;       // 393216
    float* SSUM  = CONV3 + 393216;      // 8192   [zeroed]
    float* SUMS  = SSUM  + 8192;        // 48     [zeroed]
    float* FSUM  = SUMS  + 48;          // 512    [zeroed]
    float* M2SUM = FSUM  + 512;         // 256    [zeroed]
    float* WARP  = M2SUM + 256;         // 24576  [zeroed]
    short* PK    = (short*)(WARP + 24576); // 2097152 shorts (4 MB) packed bf16 hi|lo

    float* out_fc   = (float*)d_out;
    float* out_corr = out_fc + 393216;

    // zero the atomic accumulators (SSUM..WARP contiguous, 33584 floats)
    hipMemsetAsync(SSUM, 0, (size_t)(8192 + 48 + 512 + 256 + 24576)*sizeof(float), stream);

    // feature extractors (both sides in one chain); stats fused into apply
    feat_conv<<<256,256,0,stream>>>(fa_raw, fb_raw, Wa, Wb, ba, bb, FEAT, FSUM);
    feat_apply<<<256,256,0,stream>>>(FEAT, FSUM, M2SUM);
    feat_finish<<<64,256,0,stream>>>(FEAT, M2SUM, PK);

    // fc path: 256->128 (reflect, s2), 128->64 (reflect, s2); stats fused
    conv3_kernel<2,true><<<384,256,0,stream>>>(fc_raw, 256,256, Wc1, bc1, CONV1, SUMS+0);
    inapply_kernel<<<384,256,0,stream>>>(CONV1, SUMS+0, 16384, 1.f/16384.f, CONV1);
    conv3_kernel<2,true><<<96,256,0,stream>>>(CONV1, 128,128, Wc2, bc2, FC64, SUMS+12);
    inapply_kernel<<<96,256,0,stream>>>(FC64, SUMS+12, 4096, 1.f/4096.f, FC64);

    // correlation softmax (two-pass MFMA recompute) + fused warp
    corr_mfma<0><<<2048,256,0,stream>>>(PK, out_corr, SSUM, FC64, WARP);
    corr_mfma<1><<<2048,256,0,stream>>>(PK, out_corr, SSUM, FC64, WARP);

    // upsample block 1: 64 -> 128 (up2x fused into conv)
    upconv3_kernel<64><<<384,256,0,stream>>>(WARP, Wu1, bu1, CONV2, SUMS+24);
    inapply_kernel<<<384,256,0,stream>>>(CONV2, SUMS+24, 16384, 1.f/16384.f, CONV2);

    // upsample block 2: 128 -> 256, final output
    upconv3_kernel<128><<<1536,256,0,stream>>>(CONV2, Wu2, bu2, CONV3, SUMS+36);
    inapply_kernel<<<1536,256,0,stream>>>(CONV3, SUMS+36, 65536, 1.f/65536.f, out_fc);
}